// Round 11
// baseline (493.403 us; speedup 1.0000x reference)
//
#include <hip/hip_runtime.h>
#include <hip/hip_bf16.h>
#include <math.h>

#define TM 64      // nodes per ffn tile
#define XROW 64    // xs row = 64 bytes: 4 f32 (feat*dinv, pad) + 16 bf16 (emb*dinv) + 8B pad

typedef float v2f __attribute__((ext_vector_type(2)));
typedef unsigned int uint_t;
typedef unsigned short ushort_t;

__device__ __forceinline__ v2f fma2(v2f a, v2f b, v2f c) {
    return __builtin_elementwise_fma(a, b, c);
}
__device__ __forceinline__ v2f splat2(float s) { return (v2f){s, s}; }
__device__ __forceinline__ v2f max02(v2f a) {
    return (v2f){fmaxf(a.x, 0.0f), fmaxf(a.y, 0.0f)};
}
// packed f32->bf16 RNE: dst.lo16 = bf16(lo), dst.hi16 = bf16(hi)
__device__ __forceinline__ uint_t pack_bf16(float lo, float hi) {
    uint_t r;
    asm volatile("v_cvt_pk_bf16_f32 %0, %1, %2" : "=v"(r) : "v"(lo), "v"(hi));
    return r;
}
__device__ __forceinline__ float bf16_f(ushort_t u) {
    union { uint_t i; float f; } c; c.i = ((uint_t)u) << 16; return c.f;
}
__device__ __forceinline__ float blo(uint_t u) {
    union { uint_t i; float f; } c; c.i = u << 16; return c.f;
}
__device__ __forceinline__ float bhi(uint_t u) {
    union { uint_t i; float f; } c; c.i = u & 0xffff0000u; return c.f;
}

// ---------------- fused FFN + decoder ----------------
// 256 threads = 4 waves, TM=64, wave = 32-output slice, lane = node.
// bf16 activations in LDS (16 KB) + fp32 weights via wave-uniform s_load.
// LDS 18 KB -> 8 blocks/CU -> 32 waves/CU AND single cohort (1563 <= 2048 resident).
__global__ __launch_bounds__(256, 8) void ffn_kernel(
    const float* __restrict__ coords, const float* __restrict__ features,
    const float* __restrict__ dinv,
    const float* __restrict__ fw0, const float* __restrict__ fb0,
    const float* __restrict__ fg0, const float* __restrict__ fe0,
    const float* __restrict__ fw1, const float* __restrict__ fb1,
    const float* __restrict__ fg1, const float* __restrict__ fe1,
    const float* __restrict__ fw2, const float* __restrict__ fb2,
    const float* __restrict__ fg2, const float* __restrict__ fe2,
    const float* __restrict__ fw3, const float* __restrict__ fb3,
    const float* __restrict__ dw0, const float* __restrict__ db0,
    const float* __restrict__ dw1, const float* __restrict__ db1,
    const float* __restrict__ dw2, const float* __restrict__ db2,
    char* __restrict__ xsb, int n_nodes)
{
    __shared__ ushort_t hbuf[128][TM];  // [feature][node], bf16, 16 KB
    __shared__ float ps1[4][64];        // LN partial sums
    __shared__ float ps2[4][64];        // LN partial sumsq

    const int t    = threadIdx.x;
    const int lane = t & 63;
    const int w    = __builtin_amdgcn_readfirstlane(t >> 6);
    const int jw   = w * 32;
    const int n0   = blockIdx.x * TM;

    int g = n0 + lane;
    if (g >= n_nodes) g = n_nodes - 1;

    v2f acc[16];   // outs (jw+2q, jw+2q+1), fp32

    auto lnorm = [&](const float* __restrict__ gam, const float* __restrict__ bet) {
        float s1 = 0.f, s2 = 0.f;
        #pragma unroll
        for (int q = 0; q < 16; q++) {
            s1 += acc[q].x + acc[q].y;
            s2 += acc[q].x * acc[q].x + acc[q].y * acc[q].y;
        }
        ps1[w][lane] = s1; ps2[w][lane] = s2;
        __syncthreads();
        float t1 = ps1[0][lane] + ps1[1][lane] + ps1[2][lane] + ps1[3][lane];
        float t2 = ps2[0][lane] + ps2[1][lane] + ps2[2][lane] + ps2[3][lane];
        float mean = t1 * (1.0f / 128.0f);
        float var  = t2 * (1.0f / 128.0f) - mean * mean;
        float inv  = rsqrtf(var + 1e-5f);
        v2f mean2 = splat2(mean), inv2 = splat2(inv);
        #pragma unroll
        for (int q = 0; q < 16; q++) {
            v2f gm = *(const v2f*)&gam[jw + 2 * q];   // uniform s_load
            v2f bt = *(const v2f*)&bet[jw + 2 * q];
            acc[q] = fma2((acc[q] - mean2) * inv2, gm, bt);
        }
    };

    auto store32 = [&]() {   // fp32 acc -> bf16 hbuf (RNE)
        #pragma unroll
        for (int q = 0; q < 16; q++) {
            uint_t r = pack_bf16(acc[q].x, acc[q].y);
            hbuf[jw + 2 * q][lane]     = (ushort_t)r;
            hbuf[jw + 2 * q + 1][lane] = (ushort_t)(r >> 16);
        }
    };

    auto layer128 = [&](const float* __restrict__ W, const float* __restrict__ b) {
        #pragma unroll
        for (int q = 0; q < 16; q++) acc[q] = *(const v2f*)&b[jw + 2 * q];
        #pragma unroll 4
        for (int k = 0; k < 128; k++) {
            v2f av = splat2(bf16_f(hbuf[k][lane]));
            const v2f* W2 = (const v2f*)(W + k * 128 + jw);  // uniform -> s_load
            #pragma unroll
            for (int q = 0; q < 16; q++) acc[q] = fma2(av, W2[q], acc[q]);
        }
    };

    // ---- layer 0: 2 -> 128, relu, LN ----
    {
        float2 c = *(const float2*)&coords[(size_t)g * 2];
        v2f cx = splat2(c.x), cy = splat2(c.y);
        #pragma unroll
        for (int q = 0; q < 16; q++) {
            int j = jw + 2 * q;
            v2f w0 = *(const v2f*)&fw0[j];
            v2f w1 = *(const v2f*)&fw0[128 + j];
            v2f bb = *(const v2f*)&fb0[j];
            acc[q] = max02(fma2(cx, w0, fma2(cy, w1, bb)));
        }
        lnorm(fg0, fe0);
        store32();
        __syncthreads();
    }

    // ---- layers 1..2: 128 -> 128, relu, LN ----
    layer128(fw1, fb1);
    #pragma unroll
    for (int q = 0; q < 16; q++) acc[q] = max02(acc[q]);
    lnorm(fg1, fe1);           // internal barrier covers WAR on hbuf
    store32();
    __syncthreads();

    layer128(fw2, fb2);
    #pragma unroll
    for (int q = 0; q < 16; q++) acc[q] = max02(acc[q]);
    lnorm(fg2, fe2);
    store32();
    __syncthreads();

    // ---- layer 3: 128 -> 128, relu only ----
    layer128(fw3, fb3);
    #pragma unroll
    for (int q = 0; q < 16; q++) acc[q] = max02(acc[q]);
    __syncthreads();           // all hbuf reads done before overwrite
    store32();
    __syncthreads();

    // ---- decoder D0: 128 -> 64, tanh (16 outs/wave) ----
    {
        const int j16 = w * 16;
        v2f d0[8];
        #pragma unroll
        for (int q = 0; q < 8; q++) d0[q] = *(const v2f*)&db0[j16 + 2 * q];
        #pragma unroll 4
        for (int k = 0; k < 128; k++) {
            v2f av = splat2(bf16_f(hbuf[k][lane]));
            const v2f* W2 = (const v2f*)(dw0 + k * 64 + j16);
            #pragma unroll
            for (int q = 0; q < 8; q++) d0[q] = fma2(av, W2[q], d0[q]);
        }
        #pragma unroll
        for (int q = 0; q < 8; q++) d0[q] = (v2f){tanhf(d0[q].x), tanhf(d0[q].y)};
        __syncthreads();
        #pragma unroll
        for (int q = 0; q < 8; q++) {
            uint_t r = pack_bf16(d0[q].x, d0[q].y);
            hbuf[j16 + 2 * q][lane]     = (ushort_t)r;
            hbuf[j16 + 2 * q + 1][lane] = (ushort_t)(r >> 16);
        }
        __syncthreads();
    }

    // ---- decoder D1: 64 -> 32, tanh (8 outs/wave) ----
    {
        const int j8 = w * 8;
        v2f d1[4];
        #pragma unroll
        for (int q = 0; q < 4; q++) d1[q] = *(const v2f*)&db1[j8 + 2 * q];
        #pragma unroll 4
        for (int k = 0; k < 64; k++) {
            v2f av = splat2(bf16_f(hbuf[k][lane]));
            const v2f* W2 = (const v2f*)(dw1 + k * 32 + j8);
            #pragma unroll
            for (int q = 0; q < 4; q++) d1[q] = fma2(av, W2[q], d1[q]);
        }
        #pragma unroll
        for (int q = 0; q < 4; q++) d1[q] = (v2f){tanhf(d1[q].x), tanhf(d1[q].y)};
        __syncthreads();
        #pragma unroll
        for (int q = 0; q < 4; q++) {
            uint_t r = pack_bf16(d1[q].x, d1[q].y);
            hbuf[j8 + 2 * q][lane]     = (ushort_t)r;
            hbuf[j8 + 2 * q + 1][lane] = (ushort_t)(r >> 16);
        }
        __syncthreads();
    }

    // ---- decoder D2: 32 -> 16, linear (4 outs/wave) ----
    {
        const int j4 = w * 4;
        v2f d2[2];
        #pragma unroll
        for (int q = 0; q < 2; q++) d2[q] = *(const v2f*)&db2[j4 + 2 * q];
        #pragma unroll 4
        for (int k = 0; k < 32; k++) {
            v2f av = splat2(bf16_f(hbuf[k][lane]));
            const v2f* W2 = (const v2f*)(dw2 + k * 16 + j4);
            d2[0] = fma2(av, W2[0], d2[0]);
            d2[1] = fma2(av, W2[1], d2[1]);
        }
        __syncthreads();
        #pragma unroll
        for (int q = 0; q < 2; q++) {
            uint_t r = pack_bf16(d2[q].x, d2[q].y);
            hbuf[j4 + 2 * q][lane]     = (ushort_t)r;
            hbuf[j4 + 2 * q + 1][lane] = (ushort_t)(r >> 16);
        }
        __syncthreads();
    }

    // ---- write xs row (64 B): [f0,f1,f2,0]*dinv f32 | emb0..15*dinv bf16 | pad ----
    {
        const int nn = t & 63;
        const int jg = t >> 6;             // 0..3
        int gg = n0 + nn;
        if (gg < n_nodes && jg < 3) {
            float dgg = dinv[gg];
            char* rp = xsb + (size_t)gg * XROW;
            if (jg == 0) {
                float4 f;
                f.x = features[(size_t)gg * 3 + 0] * dgg;
                f.y = features[(size_t)gg * 3 + 1] * dgg;
                f.z = features[(size_t)gg * 3 + 2] * dgg;
                f.w = 0.0f;
                *(float4*)rp = f;
            } else {
                int e0 = (jg - 1) * 8;     // emb base 0 or 8
                uint_t u[4];
                #pragma unroll
                for (int p = 0; p < 4; p++) {
                    float lo = bf16_f(hbuf[e0 + 2 * p][nn]) * dgg;
                    float hi = bf16_f(hbuf[e0 + 2 * p + 1][nn]) * dgg;
                    u[p] = pack_bf16(lo, hi);
                }
                uint4 uv = make_uint4(u[0], u[1], u[2], u[3]);
                *(uint4*)(rp + 16 + (jg - 1) * 16) = uv;
            }
        }
    }
}

// ---------------- CSR build ----------------
__global__ void deg_kernel(const int* __restrict__ row, int* __restrict__ cnt, int E_) {
    int e4 = (blockIdx.x * blockDim.x + threadIdx.x) * 4;
    if (e4 + 3 < E_) {
        int4 r = *(const int4*)&row[e4];
        atomicAdd(&cnt[r.x], 1); atomicAdd(&cnt[r.y], 1);
        atomicAdd(&cnt[r.z], 1); atomicAdd(&cnt[r.w], 1);
    } else {
        for (int e = e4; e < E_; e++) atomicAdd(&cnt[row[e]], 1);
    }
}

__global__ void scan1_kernel(const int* __restrict__ cnt, int* __restrict__ offs,
                             int* __restrict__ bsum, int n) {
    __shared__ int tmp[256];
    int t = threadIdx.x, b = blockIdx.x, i = b * 256 + t;
    int v = (i < n) ? cnt[i] : 0;
    tmp[t] = v; __syncthreads();
    #pragma unroll
    for (int d = 1; d < 256; d <<= 1) {
        int add = (t >= d) ? tmp[t - d] : 0;
        __syncthreads();
        tmp[t] += add;
        __syncthreads();
    }
    if (i < n) offs[i] = tmp[t] - v;
    if (t == 255) bsum[b] = tmp[t];
}

__global__ void scan2_kernel(int* __restrict__ bsum, int B) {
    __shared__ int tmp[512];
    int t = threadIdx.x;
    tmp[t] = (t < B) ? bsum[t] : 0; __syncthreads();
    #pragma unroll
    for (int d = 1; d < 512; d <<= 1) {
        int add = (t >= d) ? tmp[t - d] : 0;
        __syncthreads();
        tmp[t] += add;
        __syncthreads();
    }
    if (t < B) bsum[t] = tmp[t];
}

__global__ void scan3_kernel(int* __restrict__ offs, const int* __restrict__ bsum,
                             const int* __restrict__ cnt, int* __restrict__ fill,
                             float* __restrict__ dinv, int n) {
    int i = blockIdx.x * blockDim.x + threadIdx.x;
    if (i >= n) return;
    int b = i >> 8;
    int base = (b > 0) ? bsum[b - 1] : 0;
    int o = offs[i] + base;
    offs[i] = o;
    fill[i] = o;
    dinv[i] = rsqrtf((float)cnt[i] + 1.0f);
}

__global__ void scatter_kernel(const int* __restrict__ row, const int* __restrict__ col,
                               int* __restrict__ fill, int* __restrict__ es, int E_) {
    int e4 = (blockIdx.x * blockDim.x + threadIdx.x) * 4;
    if (e4 + 3 < E_) {
        int4 r = *(const int4*)&row[e4];
        int4 c = *(const int4*)&col[e4];
        es[atomicAdd(&fill[r.x], 1)] = c.x;
        es[atomicAdd(&fill[r.y], 1)] = c.y;
        es[atomicAdd(&fill[r.z], 1)] = c.z;
        es[atomicAdd(&fill[r.w], 1)] = c.w;
    } else {
        for (int e = e4; e < E_; e++) {
            int p = atomicAdd(&fill[row[e]], 1);
            es[p] = col[e];
        }
    }
}

// w_eff = cw2 @ ow (64), b_eff = cb2 @ ow + ob
__global__ void prep_kernel(const float* __restrict__ cw2, const float* __restrict__ cb2,
                            const float* __restrict__ ow, const float* __restrict__ ob,
                            float* __restrict__ wb) {
    int i = threadIdx.x;
    if (i < 64) {
        float a = 0.f;
        for (int j = 0; j < 64; j++) a += cw2[i * 64 + j] * ow[j];
        wb[i] = a;
    }
    if (i == 0) {
        float bb = 0.f;
        for (int j = 0; j < 64; j++) bb += cb2[j] * ow[j];
        wb[64] = bb + ob[0];
    }
}

// octet (8 lanes) per node: gather 64B xs rows (1 cache line/edge), unpack, reduce,
// matmul 19x64 split 8 outs/lane, relu, dot w_eff -> ss[i] = dinv[i]*s[i]
__global__ __launch_bounds__(256) void node1g_kernel(
    const int* __restrict__ offs, const int* __restrict__ cnt, const int* __restrict__ es,
    const float* __restrict__ dinv, const char* __restrict__ xsb,
    const float* __restrict__ cw1, const float* __restrict__ cb1,
    const float* __restrict__ wb, float* __restrict__ ss, int n)
{
    __shared__ float w[19 * 64];
    __shared__ float bbs[64];
    __shared__ float wes[64];
    for (int i = threadIdx.x; i < 19 * 64; i += 256) w[i] = cw1[i];
    for (int i = threadIdx.x; i < 64; i += 256) { bbs[i] = cb1[i]; wes[i] = wb[i]; }
    __syncthreads();
    const int t  = threadIdx.x;
    const int oc = t & 7;
    const int i  = blockIdx.x * 32 + (t >> 3);
    if (i >= n) return;
    const float di = dinv[i];

    float af[19];
    #pragma unroll
    for (int q = 0; q < 19; q++) af[q] = 0.f;

    auto addrow = [&](const char* rp) {
        float4 F = *(const float4*)rp;
        uint4 U0 = *(const uint4*)(rp + 16);
        uint4 U1 = *(const uint4*)(rp + 32);
        af[0] += F.x; af[1] += F.y; af[2] += F.z;
        af[3]  += blo(U0.x); af[4]  += bhi(U0.x);
        af[5]  += blo(U0.y); af[6]  += bhi(U0.y);
        af[7]  += blo(U0.z); af[8]  += bhi(U0.z);
        af[9]  += blo(U0.w); af[10] += bhi(U0.w);
        af[11] += blo(U1.x); af[12] += bhi(U1.x);
        af[13] += blo(U1.y); af[14] += bhi(U1.y);
        af[15] += blo(U1.z); af[16] += bhi(U1.z);
        af[17] += blo(U1.w); af[18] += bhi(U1.w);
    };

    if (oc == 0) addrow(xsb + (size_t)i * XROW);   // self term
    const int st = offs[i], dg = cnt[i];
    for (int e = oc; e < dg; e += 8) {
        int c = es[st + e];
        addrow(xsb + (size_t)c * XROW);
    }

    // octet reduce + scale by di
    float a19[19];
    #pragma unroll
    for (int q = 0; q < 19; q++) {
        float v = af[q];
        v += __shfl_xor(v, 1);
        v += __shfl_xor(v, 2);
        v += __shfl_xor(v, 4);
        a19[q] = v * di;
    }

    // matmul: this lane's 8 outputs j in [oc*8, oc*8+8)
    const int j0 = oc * 8;
    v2f am[4];
    const v2f* w2  = (const v2f*)w;
    const v2f* bb2 = (const v2f*)bbs;
    #pragma unroll
    for (int q = 0; q < 4; q++) am[q] = bb2[j0 / 2 + q];
    #pragma unroll
    for (int k = 0; k < 19; k++) {
        v2f v = splat2(a19[k]);
        #pragma unroll
        for (int q = 0; q < 4; q++) am[q] = fma2(v, w2[k * 32 + j0 / 2 + q], am[q]);
    }
    const v2f* we2 = (const v2f*)wes;
    v2f sv2 = {0.f, 0.f};
    #pragma unroll
    for (int q = 0; q < 4; q++) sv2 = fma2(max02(am[q]), we2[j0 / 2 + q], sv2);
    float sv = sv2.x + sv2.y;
    sv += __shfl_xor(sv, 1);
    sv += __shfl_xor(sv, 2);
    sv += __shfl_xor(sv, 4);
    if (oc == 0) ss[i] = di * sv;
}

// octet per node: out[i] = b_eff + di * (ss[i] + Σ ss[c])
__global__ __launch_bounds__(256) void outg_kernel(
    const int* __restrict__ offs, const int* __restrict__ cnt, const int* __restrict__ es,
    const float* __restrict__ dinv, const float* __restrict__ ss,
    const float* __restrict__ wb, float* __restrict__ out, int n)
{
    const int t  = threadIdx.x;
    const int oc = t & 7;
    const int i  = blockIdx.x * 32 + (t >> 3);
    if (i >= n) return;
    const int st = offs[i], dg = cnt[i];
    float sum = (oc == 0) ? ss[i] : 0.f;
    for (int e = oc; e < dg; e += 8) {
        int c = es[st + e];
        sum += ss[c];
    }
    sum += __shfl_xor(sum, 1);
    sum += __shfl_xor(sum, 2);
    sum += __shfl_xor(sum, 4);
    if (oc == 0) out[i] = wb[64] + dinv[i] * sum;
}

extern "C" void kernel_launch(void* const* d_in, const int* in_sizes, int n_in,
                              void* d_out, int out_size, void* d_ws, size_t ws_size,
                              hipStream_t stream) {
    const float* coords   = (const float*)d_in[0];
    const float* features = (const float*)d_in[1];
    const int*   eidx     = (const int*)d_in[2];
    const float* fw0 = (const float*)d_in[3];
    const float* fb0 = (const float*)d_in[4];
    const float* fg0 = (const float*)d_in[5];
    const float* fe0 = (const float*)d_in[6];
    const float* fw1 = (const float*)d_in[7];
    const float* fb1 = (const float*)d_in[8];
    const float* fg1 = (const float*)d_in[9];
    const float* fe1 = (const float*)d_in[10];
    const float* fw2 = (const float*)d_in[11];
    const float* fb2 = (const float*)d_in[12];
    const float* fg2 = (const float*)d_in[13];
    const float* fe2 = (const float*)d_in[14];
    const float* fw3 = (const float*)d_in[15];
    const float* fb3 = (const float*)d_in[16];
    const float* dw0 = (const float*)d_in[17];
    const float* db0 = (const float*)d_in[18];
    const float* dw1 = (const float*)d_in[19];
    const float* db1 = (const float*)d_in[20];
    const float* dw2 = (const float*)d_in[21];
    const float* db2 = (const float*)d_in[22];
    const float* cw1 = (const float*)d_in[23];
    const float* cb1 = (const float*)d_in[24];
    const float* cw2 = (const float*)d_in[25];
    const float* cb2 = (const float*)d_in[26];
    const float* ow  = (const float*)d_in[27];
    const float* ob  = (const float*)d_in[28];
    float* out = (float*)d_out;

    const int Nn = in_sizes[0] / 2;   // 100000
    const int E_ = in_sizes[2] / 2;   // 2000000
    const int NB = (Nn + 255) / 256;  // scan blocks (<=512)
    const int NO = (Nn * 8 + 255) / 256;  // octet-per-node blocks
    const int NT = (Nn + TM - 1) / TM;    // ffn node tiles

    char* ws = (char*)d_ws;
    size_t o = 0;
    char*  xsb  = (char*) (ws + o); o += (size_t)Nn * XROW;          // 64B rows, aligned
    int*   cnt  = (int*)  (ws + o); o += (size_t)Nn * sizeof(int);
    int*   offs = (int*)  (ws + o); o += (size_t)Nn * sizeof(int);
    int*   fill = (int*)  (ws + o); o += (size_t)Nn * sizeof(int);
    int*   bsum = (int*)  (ws + o); o += 512 * sizeof(int);
    float* dinv = (float*)(ws + o); o += (size_t)Nn * sizeof(float);
    float* ssb  = (float*)(ws + o); o += (size_t)Nn * sizeof(float);
    int*   es   = (int*)  (ws + o); o += (size_t)E_ * sizeof(int);
    float* wb   = (float*)(ws + o); o += 80 * sizeof(float);

    hipMemsetAsync(cnt, 0, (size_t)Nn * sizeof(int), stream);

    // CSR build first (produces dinv for ffn's prescale)
    deg_kernel<<<(E_ / 4 + 255) / 256, 256, 0, stream>>>(eidx, cnt, E_);
    scan1_kernel<<<NB, 256, 0, stream>>>(cnt, offs, bsum, Nn);
    scan2_kernel<<<1, 512, 0, stream>>>(bsum, NB);
    scan3_kernel<<<NB, 256, 0, stream>>>(offs, bsum, cnt, fill, dinv, Nn);
    scatter_kernel<<<(E_ / 4 + 255) / 256, 256, 0, stream>>>(eidx, eidx + E_, fill, es, E_);

    ffn_kernel<<<NT, 256, 0, stream>>>(
        coords, features, dinv,
        fw0, fb0, fg0, fe0, fw1, fb1, fg1, fe1, fw2, fb2, fg2, fe2, fw3, fb3,
        dw0, db0, dw1, db1, dw2, db2, xsb, Nn);

    prep_kernel<<<1, 64, 0, stream>>>(cw2, cb2, ow, ob, wb);
    node1g_kernel<<<NO, 256, 0, stream>>>(offs, cnt, es, dinv, xsb, cw1, cb1, wb, ssb, Nn);
    outg_kernel<<<NO, 256, 0, stream>>>(offs, cnt, es, dinv, ssb, wb, out, Nn);
}

// Round 12
// 430.081 us; speedup vs baseline: 1.1472x; 1.1472x over previous
//
#include <hip/hip_runtime.h>
#include <hip/hip_bf16.h>
#include <math.h>

#define TM 64      // nodes per ffn tile
#define XROW 64    // xs row = 64 bytes: 4 f32 (feat*dinv, pad) + 16 bf16 (emb*dinv) + 16B pad

typedef float v2f __attribute__((ext_vector_type(2)));
typedef float f32x4 __attribute__((ext_vector_type(4)));
typedef __bf16 bf16x8 __attribute__((ext_vector_type(8)));
typedef unsigned short u16x8 __attribute__((ext_vector_type(8)));
typedef unsigned int uint_t;
typedef unsigned short ushort_t;

__device__ __forceinline__ v2f fma2(v2f a, v2f b, v2f c) {
    return __builtin_elementwise_fma(a, b, c);
}
__device__ __forceinline__ v2f splat2(float s) { return (v2f){s, s}; }
__device__ __forceinline__ v2f max02(v2f a) {
    return (v2f){fmaxf(a.x, 0.0f), fmaxf(a.y, 0.0f)};
}
// packed f32->bf16 RNE
__device__ __forceinline__ uint_t pack_bf16(float lo, float hi) {
    uint_t r;
    asm volatile("v_cvt_pk_bf16_f32 %0, %1, %2" : "=v"(r) : "v"(lo), "v"(hi));
    return r;
}
__device__ __forceinline__ float bf16_f(ushort_t u) {
    union { uint_t i; float f; } c; c.i = ((uint_t)u) << 16; return c.f;
}
__device__ __forceinline__ float blo(uint_t u) {
    union { uint_t i; float f; } c; c.i = u << 16; return c.f;
}
__device__ __forceinline__ float bhi(uint_t u) {
    union { uint_t i; float f; } c; c.i = u & 0xffff0000u; return c.f;
}

// abuf byte address for (node, feat): [node][feat] bf16, XOR-swizzled 16B slots
__device__ __forceinline__ int aaddr(int node, int feat) {
    return (node * 256 + feat * 2) ^ ((node & 15) << 4);
}

// ---------------- weight pre-swizzle: W[K][N] f32 -> frag-ordered bf16 hi/lo ----------------
// layout: [h][kk][cb][lane][j] ; element = W[kk*32 + (lane>>4)*8 + j][cb*16 + (lane&15)]
__global__ void prepw_kernel(const float* __restrict__ W, ushort_t* __restrict__ out,
                             int K, int N) {
    int idx = blockIdx.x * 256 + threadIdx.x;
    int total = 2 * K * N;
    if (idx >= total) return;
    int j    = idx & 7;
    int lane = (idx >> 3) & 63;
    int rest = idx >> 9;
    int ncb  = N >> 4;
    int cb   = rest % ncb;
    int r2   = rest / ncb;
    int nkk  = K >> 5;
    int kk   = r2 % nkk;
    int h    = r2 / nkk;
    int k = kk * 32 + (lane >> 4) * 8 + j;
    int n = cb * 16 + (lane & 15);
    float wv = W[k * N + n];
    ushort_t hi = (ushort_t)pack_bf16(wv, wv);
    if (h == 0) {
        out[idx] = hi;
    } else {
        float res = wv - bf16_f(hi);
        out[idx] = (ushort_t)pack_bf16(res, res);
    }
}

// ---------------- fused FFN + decoder ----------------
// L0: scalar path + cross-wave LN -> abuf ([node][feat] bf16, swizzled)
// L1-3: MFMA 16x16x32_bf16, hi/lo split weights from pre-swizzled global (coalesced),
//       bias+relu epilogue in-place to abuf; LN per-node (4 threads/node) for L1,L2.
// transpose abuf -> tbuf ([feat][node]); decoders + xs epilogue as before on tbuf.
__global__ __launch_bounds__(256, 4) void ffn_kernel(
    const float* __restrict__ coords, const float* __restrict__ features,
    const float* __restrict__ dinv,
    const float* __restrict__ fw0, const float* __restrict__ fb0,
    const float* __restrict__ fg0, const float* __restrict__ fe0,
    const ushort_t* __restrict__ wswz,
    const float* __restrict__ fb1, const float* __restrict__ fg1, const float* __restrict__ fe1,
    const float* __restrict__ fb2, const float* __restrict__ fg2, const float* __restrict__ fe2,
    const float* __restrict__ fb3,
    const float* __restrict__ dw0, const float* __restrict__ db0,
    const float* __restrict__ dw1, const float* __restrict__ db1,
    const float* __restrict__ dw2, const float* __restrict__ db2,
    char* __restrict__ xsb, int n_nodes)
{
    __shared__ __align__(16) char abuf[16384];    // [64 nodes][128 feats] bf16, swizzled
    __shared__ ushort_t tbuf[128][64];            // [feat][node] bf16 (decoder layout)
    __shared__ float ps1[4][64];
    __shared__ float ps2[4][64];

    const int t    = threadIdx.x;
    const int lane = t & 63;
    const int w    = __builtin_amdgcn_readfirstlane(t >> 6);
    const int jw   = w * 32;
    const int n0   = blockIdx.x * TM;

    int g = n0 + lane;
    if (g >= n_nodes) g = n_nodes - 1;

    // ---- layer 0: 2 -> 128, relu, LN (old mapping), write abuf ----
    {
        v2f acc[16];
        float2 c = *(const float2*)&coords[(size_t)g * 2];
        v2f cx = splat2(c.x), cy = splat2(c.y);
        #pragma unroll
        for (int q = 0; q < 16; q++) {
            int j = jw + 2 * q;
            v2f w0 = *(const v2f*)&fw0[j];
            v2f w1 = *(const v2f*)&fw0[128 + j];
            v2f bb = *(const v2f*)&fb0[j];
            acc[q] = max02(fma2(cx, w0, fma2(cy, w1, bb)));
        }
        float s1 = 0.f, s2 = 0.f;
        #pragma unroll
        for (int q = 0; q < 16; q++) {
            s1 += acc[q].x + acc[q].y;
            s2 += acc[q].x * acc[q].x + acc[q].y * acc[q].y;
        }
        ps1[w][lane] = s1; ps2[w][lane] = s2;
        __syncthreads();
        float t1 = ps1[0][lane] + ps1[1][lane] + ps1[2][lane] + ps1[3][lane];
        float t2 = ps2[0][lane] + ps2[1][lane] + ps2[2][lane] + ps2[3][lane];
        float mean = t1 * (1.0f / 128.0f);
        float var  = t2 * (1.0f / 128.0f) - mean * mean;
        float inv  = rsqrtf(var + 1e-5f);
        v2f mean2 = splat2(mean), inv2 = splat2(inv);
        #pragma unroll
        for (int q = 0; q < 16; q++) {
            int j = jw + 2 * q;
            v2f gm = *(const v2f*)&fg0[j];
            v2f bt = *(const v2f*)&fe0[j];
            v2f o = fma2((acc[q] - mean2) * inv2, gm, bt);
            *(uint_t*)(abuf + aaddr(lane, j)) = pack_bf16(o.x, o.y);
        }
        __syncthreads();
    }

    // ---- MFMA layer: abuf = relu(abuf @ W + b), in place ----
    auto mfma_layer = [&](const ushort_t* Wb, const float* __restrict__ bias) {
        f32x4 acc[2][4] = {};
        #pragma unroll
        for (int kk = 0; kk < 4; kk++) {
            bf16x8 B[2][2];
            #pragma unroll
            for (int cb2 = 0; cb2 < 2; cb2++) {
                int cb = 2 * w + cb2;
                #pragma unroll
                for (int h = 0; h < 2; h++) {
                    const ushort_t* p = Wb + (size_t)(((h * 4 + kk) * 8 + cb) * 64 + lane) * 8;
                    B[cb2][h] = *(const bf16x8*)p;
                }
            }
            #pragma unroll
            for (int rb = 0; rb < 4; rb++) {
                int node = rb * 16 + (lane & 15);
                bf16x8 A = *(const bf16x8*)(abuf + aaddr(node, kk * 32 + (lane >> 4) * 8));
                #pragma unroll
                for (int cb2 = 0; cb2 < 2; cb2++) {
                    acc[cb2][rb] = __builtin_amdgcn_mfma_f32_16x16x32_bf16(A, B[cb2][0], acc[cb2][rb], 0, 0, 0);
                    acc[cb2][rb] = __builtin_amdgcn_mfma_f32_16x16x32_bf16(A, B[cb2][1], acc[cb2][rb], 0, 0, 0);
                }
            }
        }
        __syncthreads();   // all A reads done before overwrite
        float bv0 = bias[jw + (lane & 15)];
        float bv1 = bias[jw + 16 + (lane & 15)];
        #pragma unroll
        for (int cb2 = 0; cb2 < 2; cb2++) {
            int col = jw + cb2 * 16 + (lane & 15);
            float bv = cb2 ? bv1 : bv0;
            #pragma unroll
            for (int rb = 0; rb < 4; rb++) {
                #pragma unroll
                for (int r = 0; r < 4; r++) {
                    float v = fmaxf(acc[cb2][rb][r] + bv, 0.0f);
                    int node = rb * 16 + (lane >> 4) * 4 + r;
                    *(ushort_t*)(abuf + aaddr(node, col)) = (ushort_t)pack_bf16(v, v);
                }
            }
        }
        __syncthreads();
    };

    // ---- per-node LN on abuf (4 threads per node), in place ----
    auto ln_pass = [&](const float* __restrict__ gam, const float* __restrict__ bet) {
        int node = t >> 2;
        int part = t & 3;
        float vals[32];
        float s1 = 0.f, s2 = 0.f;
        #pragma unroll
        for (int q = 0; q < 4; q++) {
            int f0 = part * 32 + q * 8;
            u16x8 u = *(const u16x8*)(abuf + aaddr(node, f0));
            #pragma unroll
            for (int i = 0; i < 8; i++) {
                float v = bf16_f(u[i]);
                vals[q * 8 + i] = v;
                s1 += v; s2 += v * v;
            }
        }
        s1 += __shfl_xor(s1, 1); s1 += __shfl_xor(s1, 2);
        s2 += __shfl_xor(s2, 1); s2 += __shfl_xor(s2, 2);
        float mean = s1 * (1.0f / 128.0f);
        float var  = s2 * (1.0f / 128.0f) - mean * mean;
        float inv  = rsqrtf(var + 1e-5f);
        #pragma unroll
        for (int q = 0; q < 4; q++) {
            int f0 = part * 32 + q * 8;
            uint_t ov[4];
            #pragma unroll
            for (int p = 0; p < 4; p++) {
                v2f gm = *(const v2f*)&gam[f0 + 2 * p];
                v2f bt = *(const v2f*)&bet[f0 + 2 * p];
                float a = (vals[q * 8 + 2 * p]     - mean) * inv * gm.x + bt.x;
                float b = (vals[q * 8 + 2 * p + 1] - mean) * inv * gm.y + bt.y;
                ov[p] = pack_bf16(a, b);
            }
            uint4 uv = make_uint4(ov[0], ov[1], ov[2], ov[3]);
            *(uint4*)(abuf + aaddr(node, f0)) = uv;
        }
        __syncthreads();
    };

    mfma_layer(wswz,             fb1); ln_pass(fg1, fe1);
    mfma_layer(wswz + 32768,     fb2); ln_pass(fg2, fe2);
    mfma_layer(wswz + 65536,     fb3);   // relu only, no LN

    // ---- transpose abuf -> tbuf [feat][node] ----
    {
        #pragma unroll
        for (int q = 0; q < 4; q++) {
            int f0 = jw + q * 8;
            u16x8 u = *(const u16x8*)(abuf + aaddr(lane, f0));
            #pragma unroll
            for (int i = 0; i < 8; i++) tbuf[f0 + i][lane] = u[i];
        }
        __syncthreads();
    }

    // ---- decoder D0: 128 -> 64, tanh (16 outs/wave) ----
    {
        const int j16 = w * 16;
        v2f d0[8];
        #pragma unroll
        for (int q = 0; q < 8; q++) d0[q] = *(const v2f*)&db0[j16 + 2 * q];
        #pragma unroll 4
        for (int k = 0; k < 128; k++) {
            v2f av = splat2(bf16_f(tbuf[k][lane]));
            const v2f* W2 = (const v2f*)(dw0 + k * 64 + j16);
            #pragma unroll
            for (int q = 0; q < 8; q++) d0[q] = fma2(av, W2[q], d0[q]);
        }
        #pragma unroll
        for (int q = 0; q < 8; q++) d0[q] = (v2f){tanhf(d0[q].x), tanhf(d0[q].y)};
        __syncthreads();
        #pragma unroll
        for (int q = 0; q < 8; q++) {
            uint_t r = pack_bf16(d0[q].x, d0[q].y);
            tbuf[j16 + 2 * q][lane]     = (ushort_t)r;
            tbuf[j16 + 2 * q + 1][lane] = (ushort_t)(r >> 16);
        }
        __syncthreads();
    }

    // ---- decoder D1: 64 -> 32, tanh (8 outs/wave) ----
    {
        const int j8 = w * 8;
        v2f d1[4];
        #pragma unroll
        for (int q = 0; q < 4; q++) d1[q] = *(const v2f*)&db1[j8 + 2 * q];
        #pragma unroll 4
        for (int k = 0; k < 64; k++) {
            v2f av = splat2(bf16_f(tbuf[k][lane]));
            const v2f* W2 = (const v2f*)(dw1 + k * 32 + j8);
            #pragma unroll
            for (int q = 0; q < 4; q++) d1[q] = fma2(av, W2[q], d1[q]);
        }
        #pragma unroll
        for (int q = 0; q < 4; q++) d1[q] = (v2f){tanhf(d1[q].x), tanhf(d1[q].y)};
        __syncthreads();
        #pragma unroll
        for (int q = 0; q < 4; q++) {
            uint_t r = pack_bf16(d1[q].x, d1[q].y);
            tbuf[j8 + 2 * q][lane]     = (ushort_t)r;
            tbuf[j8 + 2 * q + 1][lane] = (ushort_t)(r >> 16);
        }
        __syncthreads();
    }

    // ---- decoder D2: 32 -> 16, linear (4 outs/wave) ----
    {
        const int j4 = w * 4;
        v2f d2[2];
        #pragma unroll
        for (int q = 0; q < 2; q++) d2[q] = *(const v2f*)&db2[j4 + 2 * q];
        #pragma unroll 4
        for (int k = 0; k < 32; k++) {
            v2f av = splat2(bf16_f(tbuf[k][lane]));
            const v2f* W2 = (const v2f*)(dw2 + k * 16 + j4);
            d2[0] = fma2(av, W2[0], d2[0]);
            d2[1] = fma2(av, W2[1], d2[1]);
        }
        __syncthreads();
        #pragma unroll
        for (int q = 0; q < 2; q++) {
            uint_t r = pack_bf16(d2[q].x, d2[q].y);
            tbuf[j4 + 2 * q][lane]     = (ushort_t)r;
            tbuf[j4 + 2 * q + 1][lane] = (ushort_t)(r >> 16);
        }
        __syncthreads();
    }

    // ---- write xs row (64 B): [f0,f1,f2,0]*dinv f32 | emb0..15*dinv bf16 | pad ----
    {
        const int nn = t & 63;
        const int jg = t >> 6;             // 0..3
        int gg = n0 + nn;
        if (gg < n_nodes && jg < 3) {
            float dgg = dinv[gg];
            char* rp = xsb + (size_t)gg * XROW;
            if (jg == 0) {
                float4 f;
                f.x = features[(size_t)gg * 3 + 0] * dgg;
                f.y = features[(size_t)gg * 3 + 1] * dgg;
                f.z = features[(size_t)gg * 3 + 2] * dgg;
                f.w = 0.0f;
                *(float4*)rp = f;
            } else {
                int e0 = (jg - 1) * 8;
                uint_t u[4];
                #pragma unroll
                for (int p = 0; p < 4; p++) {
                    float lo = bf16_f(tbuf[e0 + 2 * p][nn]) * dgg;
                    float hi = bf16_f(tbuf[e0 + 2 * p + 1][nn]) * dgg;
                    u[p] = pack_bf16(lo, hi);
                }
                uint4 uv = make_uint4(u[0], u[1], u[2], u[3]);
                *(uint4*)(rp + 16 + (jg - 1) * 16) = uv;
            }
        }
    }
}

// ---------------- CSR build ----------------
__global__ void deg_kernel(const int* __restrict__ row, int* __restrict__ cnt, int E_) {
    int e4 = (blockIdx.x * blockDim.x + threadIdx.x) * 4;
    if (e4 + 3 < E_) {
        int4 r = *(const int4*)&row[e4];
        atomicAdd(&cnt[r.x], 1); atomicAdd(&cnt[r.y], 1);
        atomicAdd(&cnt[r.z], 1); atomicAdd(&cnt[r.w], 1);
    } else {
        for (int e = e4; e < E_; e++) atomicAdd(&cnt[row[e]], 1);
    }
}

__global__ void scan1_kernel(const int* __restrict__ cnt, int* __restrict__ offs,
                             int* __restrict__ bsum, int n) {
    __shared__ int tmp[256];
    int t = threadIdx.x, b = blockIdx.x, i = b * 256 + t;
    int v = (i < n) ? cnt[i] : 0;
    tmp[t] = v; __syncthreads();
    #pragma unroll
    for (int d = 1; d < 256; d <<= 1) {
        int add = (t >= d) ? tmp[t - d] : 0;
        __syncthreads();
        tmp[t] += add;
        __syncthreads();
    }
    if (i < n) offs[i] = tmp[t] - v;
    if (t == 255) bsum[b] = tmp[t];
}

__global__ void scan2_kernel(int* __restrict__ bsum, int B) {
    __shared__ int tmp[512];
    int t = threadIdx.x;
    tmp[t] = (t < B) ? bsum[t] : 0; __syncthreads();
    #pragma unroll
    for (int d = 1; d < 512; d <<= 1) {
        int add = (t >= d) ? tmp[t - d] : 0;
        __syncthreads();
        tmp[t] += add;
        __syncthreads();
    }
    if (t < B) bsum[t] = tmp[t];
}

__global__ void scan3_kernel(int* __restrict__ offs, const int* __restrict__ bsum,
                             const int* __restrict__ cnt, int* __restrict__ fill,
                             float* __restrict__ dinv, int n) {
    int i = blockIdx.x * blockDim.x + threadIdx.x;
    if (i >= n) return;
    int b = i >> 8;
    int base = (b > 0) ? bsum[b - 1] : 0;
    int o = offs[i] + base;
    offs[i] = o;
    fill[i] = o;
    dinv[i] = rsqrtf((float)cnt[i] + 1.0f);
}

__global__ void scatter_kernel(const int* __restrict__ row, const int* __restrict__ col,
                               int* __restrict__ fill, int* __restrict__ es, int E_) {
    int e4 = (blockIdx.x * blockDim.x + threadIdx.x) * 4;
    if (e4 + 3 < E_) {
        int4 r = *(const int4*)&row[e4];
        int4 c = *(const int4*)&col[e4];
        es[atomicAdd(&fill[r.x], 1)] = c.x;
        es[atomicAdd(&fill[r.y], 1)] = c.y;
        es[atomicAdd(&fill[r.z], 1)] = c.z;
        es[atomicAdd(&fill[r.w], 1)] = c.w;
    } else {
        for (int e = e4; e < E_; e++) {
            int p = atomicAdd(&fill[row[e]], 1);
            es[p] = col[e];
        }
    }
}

// w_eff = cw2 @ ow (64), b_eff = cb2 @ ow + ob
__global__ void prep_kernel(const float* __restrict__ cw2, const float* __restrict__ cb2,
                            const float* __restrict__ ow, const float* __restrict__ ob,
                            float* __restrict__ wb) {
    int i = threadIdx.x;
    if (i < 64) {
        float a = 0.f;
        for (int j = 0; j < 64; j++) a += cw2[i * 64 + j] * ow[j];
        wb[i] = a;
    }
    if (i == 0) {
        float bb = 0.f;
        for (int j = 0; j < 64; j++) bb += cb2[j] * ow[j];
        wb[64] = bb + ob[0];
    }
}

// octet (8 lanes) per node: gather 64B xs rows, unpack, reduce,
// matmul 19x64 split 8 outs/lane, relu, dot w_eff -> ss[i] = dinv[i]*s[i]
__global__ __launch_bounds__(256) void node1g_kernel(
    const int* __restrict__ offs, const int* __restrict__ cnt, const int* __restrict__ es,
    const float* __restrict__ dinv, const char* __restrict__ xsb,
    const float* __restrict__ cw1, const float* __restrict__ cb1,
    const float* __restrict__ wb, float* __restrict__ ss, int n)
{
    __shared__ float w[19 * 64];
    __shared__ float bbs[64];
    __shared__ float wes[64];
    for (int i = threadIdx.x; i < 19 * 64; i += 256) w[i] = cw1[i];
    for (int i = threadIdx.x; i < 64; i += 256) { bbs[i] = cb1[i]; wes[i] = wb[i]; }
    __syncthreads();
    const int t  = threadIdx.x;
    const int oc = t & 7;
    const int i  = blockIdx.x * 32 + (t >> 3);
    if (i >= n) return;
    const float di = dinv[i];

    float af[19];
    #pragma unroll
    for (int q = 0; q < 19; q++) af[q] = 0.f;

    auto addrow = [&](const char* rp) {
        float4 F = *(const float4*)rp;
        uint4 U0 = *(const uint4*)(rp + 16);
        uint4 U1 = *(const uint4*)(rp + 32);
        af[0] += F.x; af[1] += F.y; af[2] += F.z;
        af[3]  += blo(U0.x); af[4]  += bhi(U0.x);
        af[5]  += blo(U0.y); af[6]  += bhi(U0.y);
        af[7]  += blo(U0.z); af[8]  += bhi(U0.z);
        af[9]  += blo(U0.w); af[10] += bhi(U0.w);
        af[11] += blo(U1.x); af[12] += bhi(U1.x);
        af[13] += blo(U1.y); af[14] += bhi(U1.y);
        af[15] += blo(U1.z); af[16] += bhi(U1.z);
        af[17] += blo(U1.w); af[18] += bhi(U1.w);
    };

    if (oc == 0) addrow(xsb + (size_t)i * XROW);
    const int st = offs[i], dg = cnt[i];
    for (int e = oc; e < dg; e += 8) {
        int c = es[st + e];
        addrow(xsb + (size_t)c * XROW);
    }

    float a19[19];
    #pragma unroll
    for (int q = 0; q < 19; q++) {
        float v = af[q];
        v += __shfl_xor(v, 1);
        v += __shfl_xor(v, 2);
        v += __shfl_xor(v, 4);
        a19[q] = v * di;
    }

    const int j0 = oc * 8;
    v2f am[4];
    const v2f* w2  = (const v2f*)w;
    const v2f* bb2 = (const v2f*)bbs;
    #pragma unroll
    for (int q = 0; q < 4; q++) am[q] = bb2[j0 / 2 + q];
    #pragma unroll
    for (int k = 0; k < 19; k++) {
        v2f v = splat2(a19[k]);
        #pragma unroll
        for (int q = 0; q < 4; q++) am[q] = fma2(v, w2[k * 32 + j0 / 2 + q], am[q]);
    }
    const v2f* we2 = (const v2f*)wes;
    v2f sv2 = {0.f, 0.f};
    #pragma unroll
    for (int q = 0; q < 4; q++) sv2 = fma2(max02(am[q]), we2[j0 / 2 + q], sv2);
    float sv = sv2.x + sv2.y;
    sv += __shfl_xor(sv, 1);
    sv += __shfl_xor(sv, 2);
    sv += __shfl_xor(sv, 4);
    if (oc == 0) ss[i] = di * sv;
}

// octet per node: out[i] = b_eff + di * (ss[i] + sum ss[c])
__global__ __launch_bounds__(256) void outg_kernel(
    const int* __restrict__ offs, const int* __restrict__ cnt, const int* __restrict__ es,
    const float* __restrict__ dinv, const float* __restrict__ ss,
    const float* __restrict__ wb, float* __restrict__ out, int n)
{
    const int t  = threadIdx.x;
    const int oc = t & 7;
    const int i  = blockIdx.x * 32 + (t >> 3);
    if (i >= n) return;
    const int st = offs[i], dg = cnt[i];
    float sum = (oc == 0) ? ss[i] : 0.f;
    for (int e = oc; e < dg; e += 8) {
        int c = es[st + e];
        sum += ss[c];
    }
    sum += __shfl_xor(sum, 1);
    sum += __shfl_xor(sum, 2);
    sum += __shfl_xor(sum, 4);
    if (oc == 0) out[i] = wb[64] + dinv[i] * sum;
}

extern "C" void kernel_launch(void* const* d_in, const int* in_sizes, int n_in,
                              void* d_out, int out_size, void* d_ws, size_t ws_size,
                              hipStream_t stream) {
    const float* coords   = (const float*)d_in[0];
    const float* features = (const float*)d_in[1];
    const int*   eidx     = (const int*)d_in[2];
    const float* fw0 = (const float*)d_in[3];
    const float* fb0 = (const float*)d_in[4];
    const float* fg0 = (const float*)d_in[5];
    const float* fe0 = (const float*)d_in[6];
    const float* fw1 = (const float*)d_in[7];
    const float* fb1 = (const float*)d_in[8];
    const float* fg1 = (const float*)d_in[9];
    const float* fe1 = (const float*)d_in[10];
    const float* fw2 = (const float*)d_in[11];
    const float* fb2 = (const float*)d_in[12];
    const float* fg2 = (const float*)d_in[13];
    const float* fe2 = (const float*)d_in[14];
    const float* fw3 = (const float*)d_in[15];
    const float* fb3 = (const float*)d_in[16];
    const float* dw0 = (const float*)d_in[17];
    const float* db0 = (const float*)d_in[18];
    const float* dw1 = (const float*)d_in[19];
    const float* db1 = (const float*)d_in[20];
    const float* dw2 = (const float*)d_in[21];
    const float* db2 = (const float*)d_in[22];
    const float* cw1 = (const float*)d_in[23];
    const float* cb1 = (const float*)d_in[24];
    const float* cw2 = (const float*)d_in[25];
    const float* cb2 = (const float*)d_in[26];
    const float* ow  = (const float*)d_in[27];
    const float* ob  = (const float*)d_in[28];
    float* out = (float*)d_out;

    const int Nn = in_sizes[0] / 2;   // 100000
    const int E_ = in_sizes[2] / 2;   // 2000000
    const int NB = (Nn + 255) / 256;
    const int NO = (Nn * 8 + 255) / 256;
    const int NT = (Nn + TM - 1) / TM;

    char* ws = (char*)d_ws;
    size_t o = 0;
    char*  xsb  = (char*) (ws + o); o += (size_t)Nn * XROW;
    int*   cnt  = (int*)  (ws + o); o += (size_t)Nn * sizeof(int);
    int*   offs = (int*)  (ws + o); o += (size_t)Nn * sizeof(int);
    int*   fill = (int*)  (ws + o); o += (size_t)Nn * sizeof(int);
    int*   bsum = (int*)  (ws + o); o += 512 * sizeof(int);
    float* dinv = (float*)(ws + o); o += (size_t)Nn * sizeof(float);
    float* ssb  = (float*)(ws + o); o += (size_t)Nn * sizeof(float);
    int*   es   = (int*)  (ws + o); o += (size_t)E_ * sizeof(int);
    float* wb   = (float*)(ws + o); o += 80 * sizeof(float);
    o = (o + 15) & ~(size_t)15;
    ushort_t* wswz = (ushort_t*)(ws + o); o += 3 * 32768 * sizeof(ushort_t);

    hipMemsetAsync(cnt, 0, (size_t)Nn * sizeof(int), stream);

    // weight pre-swizzle for MFMA layers (hi/lo bf16, fragment order)
    prepw_kernel<<<(32768 + 255) / 256, 256, 0, stream>>>(fw1, wswz,         128, 128);
    prepw_kernel<<<(32768 + 255) / 256, 256, 0, stream>>>(fw2, wswz + 32768, 128, 128);
    prepw_kernel<<<(32768 + 255) / 256, 256, 0, stream>>>(fw3, wswz + 65536, 128, 128);

    // CSR build (produces dinv for ffn's prescale)
    deg_kernel<<<(E_ / 4 + 255) / 256, 256, 0, stream>>>(eidx, cnt, E_);
    scan1_kernel<<<NB, 256, 0, stream>>>(cnt, offs, bsum, Nn);
    scan2_kernel<<<1, 512, 0, stream>>>(bsum, NB);
    scan3_kernel<<<NB, 256, 0, stream>>>(offs, bsum, cnt, fill, dinv, Nn);
    scatter_kernel<<<(E_ / 4 + 255) / 256, 256, 0, stream>>>(eidx, eidx + E_, fill, es, E_);

    ffn_kernel<<<NT, 256, 0, stream>>>(
        coords, features, dinv,
        fw0, fb0, fg0, fe0,
        wswz,
        fb1, fg1, fe1, fb2, fg2, fe2, fb3,
        dw0, db0, dw1, db1, dw2, db2, xsb, Nn);

    prep_kernel<<<1, 64, 0, stream>>>(cw2, cb2, ow, ob, wb);
    node1g_kernel<<<NO, 256, 0, stream>>>(offs, cnt, es, dinv, xsb, cw1, cb1, wb, ssb, Nn);
    outg_kernel<<<NO, 256, 0, stream>>>(offs, cnt, es, dinv, ssb, wb, out, Nn);
}

// Round 13
// 374.165 us; speedup vs baseline: 1.3187x; 1.1494x over previous
//
#include <hip/hip_runtime.h>
#include <hip/hip_bf16.h>
#include <math.h>

#define TM 64      // nodes per ffn tile
#define XROW 64    // xs row = 64 bytes: 4 f32 (feat*dinv, pad) + 16 bf16 (emb*dinv) + 16B pad
#define NSEG 8     // CSR segments (one per XCD via bid&7)

typedef float v2f __attribute__((ext_vector_type(2)));
typedef float f32x4 __attribute__((ext_vector_type(4)));
typedef __bf16 bf16x8 __attribute__((ext_vector_type(8)));
typedef unsigned short u16x8 __attribute__((ext_vector_type(8)));
typedef unsigned int uint_t;
typedef unsigned short ushort_t;

__device__ __forceinline__ v2f fma2(v2f a, v2f b, v2f c) {
    return __builtin_elementwise_fma(a, b, c);
}
__device__ __forceinline__ v2f splat2(float s) { return (v2f){s, s}; }
__device__ __forceinline__ v2f max02(v2f a) {
    return (v2f){fmaxf(a.x, 0.0f), fmaxf(a.y, 0.0f)};
}
__device__ __forceinline__ uint_t pack_bf16(float lo, float hi) {
    uint_t r;
    asm volatile("v_cvt_pk_bf16_f32 %0, %1, %2" : "=v"(r) : "v"(lo), "v"(hi));
    return r;
}
__device__ __forceinline__ float bf16_f(ushort_t u) {
    union { uint_t i; float f; } c; c.i = ((uint_t)u) << 16; return c.f;
}
__device__ __forceinline__ float blo(uint_t u) {
    union { uint_t i; float f; } c; c.i = u << 16; return c.f;
}
__device__ __forceinline__ float bhi(uint_t u) {
    union { uint_t i; float f; } c; c.i = u & 0xffff0000u; return c.f;
}

// abuf byte address for (node, feat): [node][feat] bf16, XOR-swizzled 16B slots
__device__ __forceinline__ int aaddr(int node, int feat) {
    return (node * 256 + feat * 2) ^ ((node & 15) << 4);
}

// ---------------- weight pre-swizzle: W[K][N] f32 -> frag-ordered bf16 hi/lo ----------------
__global__ void prepw_kernel(const float* __restrict__ W, ushort_t* __restrict__ out,
                             int K, int N) {
    int idx = blockIdx.x * 256 + threadIdx.x;
    int total = 2 * K * N;
    if (idx >= total) return;
    int j    = idx & 7;
    int lane = (idx >> 3) & 63;
    int rest = idx >> 9;
    int ncb  = N >> 4;
    int cb   = rest % ncb;
    int r2   = rest / ncb;
    int nkk  = K >> 5;
    int kk   = r2 % nkk;
    int h    = r2 / nkk;
    int k = kk * 32 + (lane >> 4) * 8 + j;
    int n = cb * 16 + (lane & 15);
    float wv = W[k * N + n];
    ushort_t hi = (ushort_t)pack_bf16(wv, wv);
    if (h == 0) {
        out[idx] = hi;
    } else {
        float res = wv - bf16_f(hi);
        out[idx] = (ushort_t)pack_bf16(res, res);
    }
}

// ---------------- fused FFN + decoder (round-12 MFMA version, unchanged) ----------------
__global__ __launch_bounds__(256, 4) void ffn_kernel(
    const float* __restrict__ coords, const float* __restrict__ features,
    const float* __restrict__ dinv,
    const float* __restrict__ fw0, const float* __restrict__ fb0,
    const float* __restrict__ fg0, const float* __restrict__ fe0,
    const ushort_t* __restrict__ wswz,
    const float* __restrict__ fb1, const float* __restrict__ fg1, const float* __restrict__ fe1,
    const float* __restrict__ fb2, const float* __restrict__ fg2, const float* __restrict__ fe2,
    const float* __restrict__ fb3,
    const float* __restrict__ dw0, const float* __restrict__ db0,
    const float* __restrict__ dw1, const float* __restrict__ db1,
    const float* __restrict__ dw2, const float* __restrict__ db2,
    char* __restrict__ xsb, int n_nodes)
{
    __shared__ __align__(16) char abuf[16384];    // [64 nodes][128 feats] bf16, swizzled
    __shared__ ushort_t tbuf[128][64];            // [feat][node] bf16 (decoder layout)
    __shared__ float ps1[4][64];
    __shared__ float ps2[4][64];

    const int t    = threadIdx.x;
    const int lane = t & 63;
    const int w    = __builtin_amdgcn_readfirstlane(t >> 6);
    const int jw   = w * 32;
    const int n0   = blockIdx.x * TM;

    int g = n0 + lane;
    if (g >= n_nodes) g = n_nodes - 1;

    // ---- layer 0: 2 -> 128, relu, LN, write abuf ----
    {
        v2f acc[16];
        float2 c = *(const float2*)&coords[(size_t)g * 2];
        v2f cx = splat2(c.x), cy = splat2(c.y);
        #pragma unroll
        for (int q = 0; q < 16; q++) {
            int j = jw + 2 * q;
            v2f w0 = *(const v2f*)&fw0[j];
            v2f w1 = *(const v2f*)&fw0[128 + j];
            v2f bb = *(const v2f*)&fb0[j];
            acc[q] = max02(fma2(cx, w0, fma2(cy, w1, bb)));
        }
        float s1 = 0.f, s2 = 0.f;
        #pragma unroll
        for (int q = 0; q < 16; q++) {
            s1 += acc[q].x + acc[q].y;
            s2 += acc[q].x * acc[q].x + acc[q].y * acc[q].y;
        }
        ps1[w][lane] = s1; ps2[w][lane] = s2;
        __syncthreads();
        float t1 = ps1[0][lane] + ps1[1][lane] + ps1[2][lane] + ps1[3][lane];
        float t2 = ps2[0][lane] + ps2[1][lane] + ps2[2][lane] + ps2[3][lane];
        float mean = t1 * (1.0f / 128.0f);
        float var  = t2 * (1.0f / 128.0f) - mean * mean;
        float inv  = rsqrtf(var + 1e-5f);
        v2f mean2 = splat2(mean), inv2 = splat2(inv);
        #pragma unroll
        for (int q = 0; q < 16; q++) {
            int j = jw + 2 * q;
            v2f gm = *(const v2f*)&fg0[j];
            v2f bt = *(const v2f*)&fe0[j];
            v2f o = fma2((acc[q] - mean2) * inv2, gm, bt);
            *(uint_t*)(abuf + aaddr(lane, j)) = pack_bf16(o.x, o.y);
        }
        __syncthreads();
    }

    auto mfma_layer = [&](const ushort_t* Wb, const float* __restrict__ bias) {
        f32x4 acc[2][4] = {};
        #pragma unroll
        for (int kk = 0; kk < 4; kk++) {
            bf16x8 B[2][2];
            #pragma unroll
            for (int cb2 = 0; cb2 < 2; cb2++) {
                int cb = 2 * w + cb2;
                #pragma unroll
                for (int h = 0; h < 2; h++) {
                    const ushort_t* p = Wb + (size_t)(((h * 4 + kk) * 8 + cb) * 64 + lane) * 8;
                    B[cb2][h] = *(const bf16x8*)p;
                }
            }
            #pragma unroll
            for (int rb = 0; rb < 4; rb++) {
                int node = rb * 16 + (lane & 15);
                bf16x8 A = *(const bf16x8*)(abuf + aaddr(node, kk * 32 + (lane >> 4) * 8));
                #pragma unroll
                for (int cb2 = 0; cb2 < 2; cb2++) {
                    acc[cb2][rb] = __builtin_amdgcn_mfma_f32_16x16x32_bf16(A, B[cb2][0], acc[cb2][rb], 0, 0, 0);
                    acc[cb2][rb] = __builtin_amdgcn_mfma_f32_16x16x32_bf16(A, B[cb2][1], acc[cb2][rb], 0, 0, 0);
                }
            }
        }
        __syncthreads();
        float bv0 = bias[jw + (lane & 15)];
        float bv1 = bias[jw + 16 + (lane & 15)];
        #pragma unroll
        for (int cb2 = 0; cb2 < 2; cb2++) {
            int col = jw + cb2 * 16 + (lane & 15);
            float bv = cb2 ? bv1 : bv0;
            #pragma unroll
            for (int rb = 0; rb < 4; rb++) {
                #pragma unroll
                for (int r = 0; r < 4; r++) {
                    float v = fmaxf(acc[cb2][rb][r] + bv, 0.0f);
                    int node = rb * 16 + (lane >> 4) * 4 + r;
                    *(ushort_t*)(abuf + aaddr(node, col)) = (ushort_t)pack_bf16(v, v);
                }
            }
        }
        __syncthreads();
    };

    auto ln_pass = [&](const float* __restrict__ gam, const float* __restrict__ bet) {
        int node = t >> 2;
        int part = t & 3;
        float vals[32];
        float s1 = 0.f, s2 = 0.f;
        #pragma unroll
        for (int q = 0; q < 4; q++) {
            int f0 = part * 32 + q * 8;
            u16x8 u = *(const u16x8*)(abuf + aaddr(node, f0));
            #pragma unroll
            for (int i = 0; i < 8; i++) {
                float v = bf16_f(u[i]);
                vals[q * 8 + i] = v;
                s1 += v; s2 += v * v;
            }
        }
        s1 += __shfl_xor(s1, 1); s1 += __shfl_xor(s1, 2);
        s2 += __shfl_xor(s2, 1); s2 += __shfl_xor(s2, 2);
        float mean = s1 * (1.0f / 128.0f);
        float var  = s2 * (1.0f / 128.0f) - mean * mean;
        float inv  = rsqrtf(var + 1e-5f);
        #pragma unroll
        for (int q = 0; q < 4; q++) {
            int f0 = part * 32 + q * 8;
            uint_t ov[4];
            #pragma unroll
            for (int p = 0; p < 4; p++) {
                v2f gm = *(const v2f*)&gam[f0 + 2 * p];
                v2f bt = *(const v2f*)&bet[f0 + 2 * p];
                float a = (vals[q * 8 + 2 * p]     - mean) * inv * gm.x + bt.x;
                float b = (vals[q * 8 + 2 * p + 1] - mean) * inv * gm.y + bt.y;
                ov[p] = pack_bf16(a, b);
            }
            uint4 uv = make_uint4(ov[0], ov[1], ov[2], ov[3]);
            *(uint4*)(abuf + aaddr(node, f0)) = uv;
        }
        __syncthreads();
    };

    mfma_layer(wswz,         fb1); ln_pass(fg1, fe1);
    mfma_layer(wswz + 32768, fb2); ln_pass(fg2, fe2);
    mfma_layer(wswz + 65536, fb3);   // relu only

    // ---- transpose abuf -> tbuf [feat][node] ----
    {
        #pragma unroll
        for (int q = 0; q < 4; q++) {
            int f0 = jw + q * 8;
            u16x8 u = *(const u16x8*)(abuf + aaddr(lane, f0));
            #pragma unroll
            for (int i = 0; i < 8; i++) tbuf[f0 + i][lane] = u[i];
        }
        __syncthreads();
    }

    // ---- decoder D0: 128 -> 64, tanh ----
    {
        const int j16 = w * 16;
        v2f d0[8];
        #pragma unroll
        for (int q = 0; q < 8; q++) d0[q] = *(const v2f*)&db0[j16 + 2 * q];
        #pragma unroll 4
        for (int k = 0; k < 128; k++) {
            v2f av = splat2(bf16_f(tbuf[k][lane]));
            const v2f* W2 = (const v2f*)(dw0 + k * 64 + j16);
            #pragma unroll
            for (int q = 0; q < 8; q++) d0[q] = fma2(av, W2[q], d0[q]);
        }
        #pragma unroll
        for (int q = 0; q < 8; q++) d0[q] = (v2f){tanhf(d0[q].x), tanhf(d0[q].y)};
        __syncthreads();
        #pragma unroll
        for (int q = 0; q < 8; q++) {
            uint_t r = pack_bf16(d0[q].x, d0[q].y);
            tbuf[j16 + 2 * q][lane]     = (ushort_t)r;
            tbuf[j16 + 2 * q + 1][lane] = (ushort_t)(r >> 16);
        }
        __syncthreads();
    }

    // ---- decoder D1: 64 -> 32, tanh ----
    {
        const int j8 = w * 8;
        v2f d1[4];
        #pragma unroll
        for (int q = 0; q < 4; q++) d1[q] = *(const v2f*)&db1[j8 + 2 * q];
        #pragma unroll 4
        for (int k = 0; k < 64; k++) {
            v2f av = splat2(bf16_f(tbuf[k][lane]));
            const v2f* W2 = (const v2f*)(dw1 + k * 32 + j8);
            #pragma unroll
            for (int q = 0; q < 4; q++) d1[q] = fma2(av, W2[q], d1[q]);
        }
        #pragma unroll
        for (int q = 0; q < 4; q++) d1[q] = (v2f){tanhf(d1[q].x), tanhf(d1[q].y)};
        __syncthreads();
        #pragma unroll
        for (int q = 0; q < 4; q++) {
            uint_t r = pack_bf16(d1[q].x, d1[q].y);
            tbuf[j8 + 2 * q][lane]     = (ushort_t)r;
            tbuf[j8 + 2 * q + 1][lane] = (ushort_t)(r >> 16);
        }
        __syncthreads();
    }

    // ---- decoder D2: 32 -> 16, linear ----
    {
        const int j4 = w * 4;
        v2f d2[2];
        #pragma unroll
        for (int q = 0; q < 2; q++) d2[q] = *(const v2f*)&db2[j4 + 2 * q];
        #pragma unroll 4
        for (int k = 0; k < 32; k++) {
            v2f av = splat2(bf16_f(tbuf[k][lane]));
            const v2f* W2 = (const v2f*)(dw2 + k * 16 + j4);
            d2[0] = fma2(av, W2[0], d2[0]);
            d2[1] = fma2(av, W2[1], d2[1]);
        }
        __syncthreads();
        #pragma unroll
        for (int q = 0; q < 2; q++) {
            uint_t r = pack_bf16(d2[q].x, d2[q].y);
            tbuf[j4 + 2 * q][lane]     = (ushort_t)r;
            tbuf[j4 + 2 * q + 1][lane] = (ushort_t)(r >> 16);
        }
        __syncthreads();
    }

    // ---- write xs row (64 B) ----
    {
        const int nn = t & 63;
        const int jg = t >> 6;
        int gg = n0 + nn;
        if (gg < n_nodes && jg < 3) {
            float dgg = dinv[gg];
            char* rp = xsb + (size_t)gg * XROW;
            if (jg == 0) {
                float4 f;
                f.x = features[(size_t)gg * 3 + 0] * dgg;
                f.y = features[(size_t)gg * 3 + 1] * dgg;
                f.z = features[(size_t)gg * 3 + 2] * dgg;
                f.w = 0.0f;
                *(float4*)rp = f;
            } else {
                int e0 = (jg - 1) * 8;
                uint_t u[4];
                #pragma unroll
                for (int p = 0; p < 4; p++) {
                    float lo = bf16_f(tbuf[e0 + 2 * p][nn]) * dgg;
                    float hi = bf16_f(tbuf[e0 + 2 * p + 1][nn]) * dgg;
                    u[p] = pack_bf16(lo, hi);
                }
                uint4 uv = make_uint4(u[0], u[1], u[2], u[3]);
                *(uint4*)(rp + 16 + (jg - 1) * 16) = uv;
            }
        }
    }
}

// ---------------- segmented CSR build (segment = blockIdx & 7, matches XCD round-robin) ----------------
// deg8: count per (segment, node). SAME edge->block mapping as scatter.
__global__ void deg8_kernel(const int* __restrict__ row, int* __restrict__ cnt8,
                            int E_, int Nn) {
    int s = blockIdx.x & (NSEG - 1);
    int* cs = cnt8 + (size_t)s * Nn;
    int e4 = (blockIdx.x * blockDim.x + threadIdx.x) * 4;
    if (e4 + 3 < E_) {
        int4 r = *(const int4*)&row[e4];
        atomicAdd(&cs[r.x], 1); atomicAdd(&cs[r.y], 1);
        atomicAdd(&cs[r.z], 1); atomicAdd(&cs[r.w], 1);
    } else {
        for (int e = e4; e < E_; e++) atomicAdd(&cs[row[e]], 1);
    }
}

// scan1: 2048 elements/block (8 per thread), exclusive prefix within block
__global__ void scan1_kernel(const int* __restrict__ in, int* __restrict__ out,
                             int* __restrict__ bsum, int n) {
    __shared__ int tmp[256];
    int t = threadIdx.x, b = blockIdx.x;
    int base = b * 2048 + t * 8;
    int v[8]; int s = 0;
    #pragma unroll
    for (int q = 0; q < 8; q++) {
        int idx = base + q;
        v[q] = (idx < n) ? in[idx] : 0;
        s += v[q];
    }
    tmp[t] = s; __syncthreads();
    #pragma unroll
    for (int d = 1; d < 256; d <<= 1) {
        int add = (t >= d) ? tmp[t - d] : 0;
        __syncthreads();
        tmp[t] += add;
        __syncthreads();
    }
    int run = tmp[t] - s;   // exclusive prefix of this thread's chunk
    #pragma unroll
    for (int q = 0; q < 8; q++) {
        int idx = base + q;
        if (idx < n) out[idx] = run;
        run += v[q];
    }
    if (t == 255) bsum[b] = tmp[t];
}

__global__ void scan2_kernel(int* __restrict__ bsum, int B) {
    __shared__ int tmp[512];
    int t = threadIdx.x;
    tmp[t] = (t < B) ? bsum[t] : 0; __syncthreads();
    #pragma unroll
    for (int d = 1; d < 512; d <<= 1) {
        int add = (t >= d) ? tmp[t - d] : 0;
        __syncthreads();
        tmp[t] += add;
        __syncthreads();
    }
    if (t < B) bsum[t] = tmp[t];
}

// add block bases (inclusive bsum of previous blocks)
__global__ void scanfix_kernel(int* __restrict__ data, const int* __restrict__ bsum, int n) {
    int i = blockIdx.x * 256 + threadIdx.x;
    if (i >= n) return;
    int b = i >> 11;   // /2048
    if (b > 0) data[i] += bsum[b - 1];
}

__global__ void dinv_kernel(const int* __restrict__ cnt8, float* __restrict__ dinv, int Nn) {
    int i = blockIdx.x * 256 + threadIdx.x;
    if (i >= Nn) return;
    int s = 0;
    #pragma unroll
    for (int q = 0; q < NSEG; q++) s += cnt8[(size_t)q * Nn + i];
    dinv[i] = rsqrtf((float)s + 1.0f);
}

// scatter into segment-private region: all writes to a given es line come from one XCD
__global__ void scatter_kernel(const int* __restrict__ row, const int* __restrict__ col,
                               int* __restrict__ fill8, int* __restrict__ es,
                               int E_, int Nn) {
    int s = blockIdx.x & (NSEG - 1);
    int* fs = fill8 + (size_t)s * Nn;
    int e4 = (blockIdx.x * blockDim.x + threadIdx.x) * 4;
    if (e4 + 3 < E_) {
        int4 r = *(const int4*)&row[e4];
        int4 c = *(const int4*)&col[e4];
        es[atomicAdd(&fs[r.x], 1)] = c.x;
        es[atomicAdd(&fs[r.y], 1)] = c.y;
        es[atomicAdd(&fs[r.z], 1)] = c.z;
        es[atomicAdd(&fs[r.w], 1)] = c.w;
    } else {
        for (int e = e4; e < E_; e++) {
            int p = atomicAdd(&fs[row[e]], 1);
            es[p] = col[e];
        }
    }
}

// w_eff = cw2 @ ow (64), b_eff = cb2 @ ow + ob
__global__ void prep_kernel(const float* __restrict__ cw2, const float* __restrict__ cb2,
                            const float* __restrict__ ow, const float* __restrict__ ob,
                            float* __restrict__ wb) {
    int i = threadIdx.x;
    if (i < 64) {
        float a = 0.f;
        for (int j = 0; j < 64; j++) a += cw2[i * 64 + j] * ow[j];
        wb[i] = a;
    }
    if (i == 0) {
        float bb = 0.f;
        for (int j = 0; j < 64; j++) bb += cb2[j] * ow[j];
        wb[64] = bb + ob[0];
    }
}

// octet per node: lane oc walks CSR segment oc [fill8-cnt8, fill8)
__global__ __launch_bounds__(256) void node1g_kernel(
    const int* __restrict__ fill8, const int* __restrict__ cnt8, const int* __restrict__ es,
    const float* __restrict__ dinv, const char* __restrict__ xsb,
    const float* __restrict__ cw1, const float* __restrict__ cb1,
    const float* __restrict__ wb, float* __restrict__ ss, int n)
{
    __shared__ float w[19 * 64];
    __shared__ float bbs[64];
    __shared__ float wes[64];
    for (int i = threadIdx.x; i < 19 * 64; i += 256) w[i] = cw1[i];
    for (int i = threadIdx.x; i < 64; i += 256) { bbs[i] = cb1[i]; wes[i] = wb[i]; }
    __syncthreads();
    const int t  = threadIdx.x;
    const int oc = t & 7;
    const int i  = blockIdx.x * 32 + (t >> 3);
    if (i >= n) return;
    const float di = dinv[i];

    float af[19];
    #pragma unroll
    for (int q = 0; q < 19; q++) af[q] = 0.f;

    auto addrow = [&](const char* rp) {
        float4 F = *(const float4*)rp;
        uint4 U0 = *(const uint4*)(rp + 16);
        uint4 U1 = *(const uint4*)(rp + 32);
        af[0] += F.x; af[1] += F.y; af[2] += F.z;
        af[3]  += blo(U0.x); af[4]  += bhi(U0.x);
        af[5]  += blo(U0.y); af[6]  += bhi(U0.y);
        af[7]  += blo(U0.z); af[8]  += bhi(U0.z);
        af[9]  += blo(U0.w); af[10] += bhi(U0.w);
        af[11] += blo(U1.x); af[12] += bhi(U1.x);
        af[13] += blo(U1.y); af[14] += bhi(U1.y);
        af[15] += blo(U1.z); af[16] += bhi(U1.z);
        af[17] += blo(U1.w); af[18] += bhi(U1.w);
    };

    if (oc == 0) addrow(xsb + (size_t)i * XROW);   // self term
    const int end = fill8[(size_t)oc * n + i];     // post-scatter = segment end
    const int dgs = cnt8[(size_t)oc * n + i];
    for (int e = end - dgs; e < end; e++) {
        int c = es[e];
        addrow(xsb + (size_t)c * XROW);
    }

    float a19[19];
    #pragma unroll
    for (int q = 0; q < 19; q++) {
        float v = af[q];
        v += __shfl_xor(v, 1);
        v += __shfl_xor(v, 2);
        v += __shfl_xor(v, 4);
        a19[q] = v * di;
    }

    const int j0 = oc * 8;
    v2f am[4];
    const v2f* w2  = (const v2f*)w;
    const v2f* bb2 = (const v2f*)bbs;
    #pragma unroll
    for (int q = 0; q < 4; q++) am[q] = bb2[j0 / 2 + q];
    #pragma unroll
    for (int k = 0; k < 19; k++) {
        v2f v = splat2(a19[k]);
        #pragma unroll
        for (int q = 0; q < 4; q++) am[q] = fma2(v, w2[k * 32 + j0 / 2 + q], am[q]);
    }
    const v2f* we2 = (const v2f*)wes;
    v2f sv2 = {0.f, 0.f};
    #pragma unroll
    for (int q = 0; q < 4; q++) sv2 = fma2(max02(am[q]), we2[j0 / 2 + q], sv2);
    float sv = sv2.x + sv2.y;
    sv += __shfl_xor(sv, 1);
    sv += __shfl_xor(sv, 2);
    sv += __shfl_xor(sv, 4);
    if (oc == 0) ss[i] = di * sv;
}

// octet per node: out[i] = b_eff + di * (ss[i] + sum ss[c]); lane oc walks segment oc
__global__ __launch_bounds__(256) void outg_kernel(
    const int* __restrict__ fill8, const int* __restrict__ cnt8, const int* __restrict__ es,
    const float* __restrict__ dinv, const float* __restrict__ ss,
    const float* __restrict__ wb, float* __restrict__ out, int n)
{
    const int t  = threadIdx.x;
    const int oc = t & 7;
    const int i  = blockIdx.x * 32 + (t >> 3);
    if (i >= n) return;
    const int end = fill8[(size_t)oc * n + i];
    const int dgs = cnt8[(size_t)oc * n + i];
    float sum = (oc == 0) ? ss[i] : 0.f;
    for (int e = end - dgs; e < end; e++) {
        int c = es[e];
        sum += ss[c];
    }
    sum += __shfl_xor(sum, 1);
    sum += __shfl_xor(sum, 2);
    sum += __shfl_xor(sum, 4);
    if (oc == 0) out[i] = wb[64] + dinv[i] * sum;
}

extern "C" void kernel_launch(void* const* d_in, const int* in_sizes, int n_in,
                              void* d_out, int out_size, void* d_ws, size_t ws_size,
                              hipStream_t stream) {
    const float* coords   = (const float*)d_in[0];
    const float* features = (const float*)d_in[1];
    const int*   eidx     = (const int*)d_in[2];
    const float* fw0 = (const float*)d_in[3];
    const float* fb0 = (const float*)d_in[4];
    const float* fg0 = (const float*)d_in[5];
    const float* fe0 = (const float*)d_in[6];
    const float* fw1 = (const float*)d_in[7];
    const float* fb1 = (const float*)d_in[8];
    const float* fg1 = (const float*)d_in[9];
    const float* fe1 = (const float*)d_in[10];
    const float* fw2 = (const float*)d_in[11];
    const float* fb2 = (const float*)d_in[12];
    const float* fg2 = (const float*)d_in[13];
    const float* fe2 = (const float*)d_in[14];
    const float* fw3 = (const float*)d_in[15];
    const float* fb3 = (const float*)d_in[16];
    const float* dw0 = (const float*)d_in[17];
    const float* db0 = (const float*)d_in[18];
    const float* dw1 = (const float*)d_in[19];
    const float* db1 = (const float*)d_in[20];
    const float* dw2 = (const float*)d_in[21];
    const float* db2 = (const float*)d_in[22];
    const float* cw1 = (const float*)d_in[23];
    const float* cb1 = (const float*)d_in[24];
    const float* cw2 = (const float*)d_in[25];
    const float* cb2 = (const float*)d_in[26];
    const float* ow  = (const float*)d_in[27];
    const float* ob  = (const float*)d_in[28];
    float* out = (float*)d_out;

    const int Nn = in_sizes[0] / 2;   // 100000
    const int E_ = in_sizes[2] / 2;   // 2000000
    const int n8 = NSEG * Nn;         // 800000 segmented counters
    const int NBS = (n8 + 2047) / 2048;     // scan1 blocks (<=512)
    const int NO = (Nn * 8 + 255) / 256;    // octet-per-node blocks
    const int NT = (Nn + TM - 1) / TM;      // ffn node tiles
    const int NE = (E_ / 4 + 255) / 256;    // edge blocks (deg8 & scatter share this)

    char* ws = (char*)d_ws;
    size_t o = 0;
    char*  xsb   = (char*) (ws + o); o += (size_t)Nn * XROW;
    int*   cnt8  = (int*)  (ws + o); o += (size_t)n8 * sizeof(int);
    int*   fill8 = (int*)  (ws + o); o += (size_t)n8 * sizeof(int);
    int*   bsum  = (int*)  (ws + o); o += 512 * sizeof(int);
    float* dinv  = (float*)(ws + o); o += (size_t)Nn * sizeof(float);
    float* ssb   = (float*)(ws + o); o += (size_t)Nn * sizeof(float);
    int*   es    = (int*)  (ws + o); o += (size_t)E_ * sizeof(int);
    float* wb    = (float*)(ws + o); o += 80 * sizeof(float);
    o = (o + 15) & ~(size_t)15;
    ushort_t* wswz = (ushort_t*)(ws + o); o += 3 * 32768 * sizeof(ushort_t);

    hipMemsetAsync(cnt8, 0, (size_t)n8 * sizeof(int), stream);

    // weight pre-swizzle for MFMA layers
    prepw_kernel<<<(32768 + 255) / 256, 256, 0, stream>>>(fw1, wswz,         128, 128);
    prepw_kernel<<<(32768 + 255) / 256, 256, 0, stream>>>(fw2, wswz + 32768, 128, 128);
    prepw_kernel<<<(32768 + 255) / 256, 256, 0, stream>>>(fw3, wswz + 65536, 128, 128);

    // segmented CSR build
    deg8_kernel<<<NE, 256, 0, stream>>>(eidx, cnt8, E_, Nn);
    scan1_kernel<<<NBS, 256, 0, stream>>>(cnt8, fill8, bsum, n8);
    scan2_kernel<<<1, 512, 0, stream>>>(bsum, NBS);
    scanfix_kernel<<<(n8 + 255) / 256, 256, 0, stream>>>(fill8, bsum, n8);
    dinv_kernel<<<(Nn + 255) / 256, 256, 0, stream>>>(cnt8, dinv, Nn);
    scatter_kernel<<<NE, 256, 0, stream>>>(eidx, eidx + E_, fill8, es, E_, Nn);

    ffn_kernel<<<NT, 256, 0, stream>>>(
        coords, features, dinv,
        fw0, fb0, fg0, fe0,
        wswz,
        fb1, fg1, fe1, fb2, fg2, fe2, fb3,
        dw0, db0, dw1, db1, dw2, db2, xsb, Nn);

    prep_kernel<<<1, 64, 0, stream>>>(cw2, cb2, ow, ob, wb);
    node1g_kernel<<<NO, 256, 0, stream>>>(fill8, cnt8, es, dinv, xsb, cw1, cb1, wb, ssb, Nn);
    outg_kernel<<<NO, 256, 0, stream>>>(fill8, cnt8, es, dinv, ssb, wb, out, Nn);
}